// Round 1
// baseline (7211.630 us; speedup 1.0000x reference)
//
#include <hip/hip_runtime.h>
#include <hip/hip_bf16.h>
#include <math.h>

// ---------------- constants ----------------
#define BATCH 32
#define DMODEL 768
#define HEADS 12
#define DH 64
#define DEPTH 12
#define FF 3072
#define NTOK 197
#define NPAD 208           // 13*16, M = 32*208 = 6656 = 52*128
#define MROWS (BATCH * NPAD)   // 6656
#define GRID14 14
#define NPATCH 196
#define MPATCH (BATCH * NPATCH) // 6272 = 49*128

typedef __attribute__((ext_vector_type(8))) short bf16x8;
typedef __attribute__((ext_vector_type(4))) float f32x4;

// ---------------- fp32 -> bf16 convert ----------------
__global__ __launch_bounds__(256) void cvt_bf16(const float4* __restrict__ in,
                                                ushort4* __restrict__ out, int n4) {
  int i = blockIdx.x * 256 + threadIdx.x;
  if (i < n4) {
    float4 v = in[i];
    __hip_bfloat16 a = __float2bfloat16(v.x), b = __float2bfloat16(v.y);
    __hip_bfloat16 c = __float2bfloat16(v.z), d = __float2bfloat16(v.w);
    ushort4 r;
    r.x = *(unsigned short*)&a; r.y = *(unsigned short*)&b;
    r.z = *(unsigned short*)&c; r.w = *(unsigned short*)&d;
    out[i] = r;
  }
}

// ---------------- patch gather: x[b,c,224,224] -> A[6272][768] bf16 ----------------
__global__ __launch_bounds__(256) void patch_gather(const float* __restrict__ x,
                                                    __hip_bfloat16* __restrict__ ap) {
  long long idx = (long long)blockIdx.x * 256 + threadIdx.x;
  if (idx >= (long long)MPATCH * DMODEL) return;
  int k = (int)(idx % DMODEL);
  int m = (int)(idx / DMODEL);
  int b = m / NPATCH, g = m % NPATCH;
  int gh = g / GRID14, gw = g % GRID14;
  int c = k >> 8, r = k & 255, p = r >> 4, q = r & 15;
  float v = x[(((long long)(b * 3 + c) * 224) + gh * 16 + p) * 224 + gw * 16 + q];
  ap[idx] = __float2bfloat16(v);
}

// ---------------- assemble h: cls/emb + pos, pads = 0 ----------------
__global__ __launch_bounds__(256) void assemble_h(const float* __restrict__ emb,
                                                  const float* __restrict__ cls,
                                                  const float* __restrict__ pos,
                                                  float* __restrict__ h) {
  long long idx = (long long)blockIdx.x * 256 + threadIdx.x;
  if (idx >= (long long)MROWS * DMODEL) return;
  int d = (int)(idx % DMODEL);
  int row = (int)(idx / DMODEL);
  int n = row % NPAD, b = row / NPAD;
  float v;
  if (n == 0) v = cls[d] + pos[d];
  else if (n <= NPATCH) v = emb[((long long)b * NPATCH + (n - 1)) * DMODEL + d] + pos[(long long)n * DMODEL + d];
  else v = 0.f;
  h[idx] = v;
}

// ---------------- LayerNorm (fp32 in -> bf16 out), one block per row ----------------
__global__ __launch_bounds__(256) void ln_bf16(const float* __restrict__ x,
                                               const float* __restrict__ g,
                                               const float* __restrict__ bt,
                                               __hip_bfloat16* __restrict__ y) {
  int row = blockIdx.x, t = threadIdx.x;
  const float* xr = x + (long long)row * DMODEL;
  float x0 = xr[t], x1 = xr[t + 256], x2 = xr[t + 512];
  float s = x0 + x1 + x2, ss = x0 * x0 + x1 * x1 + x2 * x2;
  for (int off = 32; off; off >>= 1) { s += __shfl_xor(s, off); ss += __shfl_xor(ss, off); }
  __shared__ float red[8];
  int w = t >> 6;
  if ((t & 63) == 0) { red[w] = s; red[w + 4] = ss; }
  __syncthreads();
  s = red[0] + red[1] + red[2] + red[3];
  ss = red[4] + red[5] + red[6] + red[7];
  float mu = s * (1.f / DMODEL);
  float inv = rsqrtf(ss * (1.f / DMODEL) - mu * mu + 1e-6f);
  long long base = (long long)row * DMODEL;
  y[base + t]       = __float2bfloat16((x0 - mu) * inv * g[t] + bt[t]);
  y[base + t + 256] = __float2bfloat16((x1 - mu) * inv * g[t + 256] + bt[t + 256]);
  y[base + t + 512] = __float2bfloat16((x2 - mu) * inv * g[t + 512] + bt[t + 512]);
}

// ---------------- final LayerNorm -> fp32 packed [B,197,768] ----------------
__global__ __launch_bounds__(256) void ln_out(const float* __restrict__ x,
                                              const float* __restrict__ g,
                                              const float* __restrict__ bt,
                                              float* __restrict__ out) {
  int idx = blockIdx.x, t = threadIdx.x;
  int b = idx / NTOK, n = idx % NTOK;
  const float* xr = x + ((long long)b * NPAD + n) * DMODEL;
  float x0 = xr[t], x1 = xr[t + 256], x2 = xr[t + 512];
  float s = x0 + x1 + x2, ss = x0 * x0 + x1 * x1 + x2 * x2;
  for (int off = 32; off; off >>= 1) { s += __shfl_xor(s, off); ss += __shfl_xor(ss, off); }
  __shared__ float red[8];
  int w = t >> 6;
  if ((t & 63) == 0) { red[w] = s; red[w + 4] = ss; }
  __syncthreads();
  s = red[0] + red[1] + red[2] + red[3];
  ss = red[4] + red[5] + red[6] + red[7];
  float mu = s * (1.f / DMODEL);
  float inv = rsqrtf(ss * (1.f / DMODEL) - mu * mu + 1e-6f);
  long long base = (long long)idx * DMODEL;
  out[base + t]       = (x0 - mu) * inv * g[t] + bt[t];
  out[base + t + 256] = (x1 - mu) * inv * g[t + 256] + bt[t + 256];
  out[base + t + 512] = (x2 - mu) * inv * g[t + 512] + bt[t + 512];
}

// ---------------- MFMA GEMM: C[m,n] = sum_k A[m,k]*B[n,k] + bias[n] ----------------
#define BM 128
#define BN 128
#define BKK 64

__device__ __forceinline__ void stage_tile(const __hip_bfloat16* __restrict__ g, int ldg,
                                           __hip_bfloat16* lds, int w, int l) {
#pragma unroll
  for (int c = 0; c < 4; ++c) {
    int rb = (c * 4 + w) * 8;                     // wave-uniform row base
    const __hip_bfloat16* gp = g + (long long)(rb + (l >> 3)) * ldg + (l & 7) * 8;
    __builtin_amdgcn_global_load_lds(
        (const __attribute__((address_space(1))) unsigned int*)(const void*)gp,
        (__attribute__((address_space(3))) unsigned int*)(void*)(lds + rb * BKK), 16, 0, 0);
  }
}

__device__ __forceinline__ void store_out(float* p, float v) { *p = v; }
__device__ __forceinline__ void store_out(__hip_bfloat16* p, float v) { *p = __float2bfloat16(v); }

template <typename OutT, bool GELU_ACT, bool RESID>
__global__ __launch_bounds__(256) void gemm_bt(const __hip_bfloat16* __restrict__ A,
                                               const __hip_bfloat16* __restrict__ Bw,
                                               const float* __restrict__ bias,
                                               OutT* __restrict__ C,
                                               const float* __restrict__ res,
                                               int M, int N, int K) {
  __shared__ __hip_bfloat16 As[BM * BKK];
  __shared__ __hip_bfloat16 Bs[BN * BKK];
  int tid = threadIdx.x, l = tid & 63, w = tid >> 6;
  int wr = w >> 1, wc = w & 1;
  int bm0 = blockIdx.y * BM, bn0 = blockIdx.x * BN;
  f32x4 acc[4][4] = {};
  for (int kt = 0; kt < K; kt += BKK) {
    __syncthreads();
    stage_tile(A + (long long)bm0 * K + kt, K, As, w, l);
    stage_tile(Bw + (long long)bn0 * K + kt, K, Bs, w, l);
    __syncthreads();
    int lr = l & 15;
#pragma unroll
    for (int ks = 0; ks < 2; ++ks) {
      int lk = ks * 32 + (l >> 4) * 8;
      bf16x8 a[4], b[4];
#pragma unroll
      for (int i = 0; i < 4; ++i)
        a[i] = *(const bf16x8*)&As[(wr * 64 + i * 16 + lr) * BKK + lk];
#pragma unroll
      for (int i = 0; i < 4; ++i)
        b[i] = *(const bf16x8*)&Bs[(wc * 64 + i * 16 + lr) * BKK + lk];
#pragma unroll
      for (int i = 0; i < 4; ++i)
#pragma unroll
        for (int j = 0; j < 4; ++j)
          acc[i][j] = __builtin_amdgcn_mfma_f32_16x16x32_bf16(a[i], b[j], acc[i][j], 0, 0, 0);
    }
  }
  int lr = l & 15, lq = l >> 4;
#pragma unroll
  for (int i = 0; i < 4; ++i) {
#pragma unroll
    for (int j = 0; j < 4; ++j) {
      int col = bn0 + wc * 64 + j * 16 + lr;
      float bv = bias[col];
#pragma unroll
      for (int r = 0; r < 4; ++r) {
        int row = bm0 + wr * 64 + i * 16 + lq * 4 + r;
        float v = acc[i][j][r] + bv;
        if (GELU_ACT) v = 0.5f * v * (1.f + erff(v * 0.70710678f));
        if (RESID) v += res[(long long)row * N + col];
        store_out(&C[(long long)row * N + col], v);
      }
    }
  }
}

// ---------------- attention (VALU round-0): block per (qhalf, head, batch) ----------------
__global__ __launch_bounds__(256) void attn_kernel(const __hip_bfloat16* __restrict__ qkv,
                                                   __hip_bfloat16* __restrict__ o) {
  __shared__ __hip_bfloat16 KT[64 * NPAD];   // KT[d][m]
  __shared__ __hip_bfloat16 Vs[NPAD * 64];   // Vs[m][d]
  __shared__ float ps[4][NPAD];
  const int qh = blockIdx.x, hd = blockIdx.y, b = blockIdx.z;
  const int tid = threadIdx.x, l = tid & 63, w = tid >> 6;
  const long long bb = (long long)b * NPAD * 2304;
  {
    int d = tid & 63, m0 = tid >> 6;
    for (int m = m0; m < NTOK; m += 4) {
      long long src = bb + (long long)m * 2304 + hd * 64 + d;
      KT[d * NPAD + m] = qkv[src + 768];
      Vs[m * 64 + d] = qkv[src + 1536];
    }
  }
  __syncthreads();
  const int nbeg = qh ? 100 : 0;
  const int nend = qh ? NTOK : 100;
  for (int n = nbeg + w; n < nend; n += 4) {
    float qv = 0.125f * __bfloat162float(qkv[bb + (long long)n * 2304 + hd * 64 + l]);
    float s0 = 0.f, s1 = 0.f, s2 = 0.f, s3 = 0.f;
#pragma unroll 8
    for (int d = 0; d < 64; ++d) {
      float qd = __shfl(qv, d);
      s0 += qd * __bfloat162float(KT[d * NPAD + l]);
      s1 += qd * __bfloat162float(KT[d * NPAD + l + 64]);
      s2 += qd * __bfloat162float(KT[d * NPAD + l + 128]);
      if (l < 5) s3 += qd * __bfloat162float(KT[d * NPAD + l + 192]);
    }
    float mx = fmaxf(fmaxf(s0, s1), s2);
    if (l < 5) mx = fmaxf(mx, s3);
    for (int off = 32; off; off >>= 1) mx = fmaxf(mx, __shfl_xor(mx, off));
    float e0 = __expf(s0 - mx), e1 = __expf(s1 - mx), e2 = __expf(s2 - mx);
    float e3 = (l < 5) ? __expf(s3 - mx) : 0.f;
    float sm = e0 + e1 + e2 + e3;
    for (int off = 32; off; off >>= 1) sm += __shfl_xor(sm, off);
    float inv = 1.f / sm;
    ps[w][l] = e0 * inv;
    ps[w][l + 64] = e1 * inv;
    ps[w][l + 128] = e2 * inv;
    if (l < 5) ps[w][l + 192] = e3 * inv;
    float oa = 0.f;
    for (int m4 = 0; m4 < 196; m4 += 4) {
      float4 p4 = *(const float4*)&ps[w][m4];
      oa += p4.x * __bfloat162float(Vs[(m4 + 0) * 64 + l]);
      oa += p4.y * __bfloat162float(Vs[(m4 + 1) * 64 + l]);
      oa += p4.z * __bfloat162float(Vs[(m4 + 2) * 64 + l]);
      oa += p4.w * __bfloat162float(Vs[(m4 + 3) * 64 + l]);
    }
    oa += ps[w][196] * __bfloat162float(Vs[196 * 64 + l]);
    o[(long long)(b * NPAD + n) * DMODEL + hd * 64 + l] = __float2bfloat16(oa);
  }
  if (qh) {  // zero pad rows so proj-GEMM A is clean
    for (int n = NTOK + w; n < NPAD; n += 4)
      o[(long long)(b * NPAD + n) * DMODEL + hd * 64 + l] = __float2bfloat16(0.f);
  }
}

// ---------------- host launch ----------------
extern "C" void kernel_launch(void* const* d_in, const int* in_sizes, int n_in,
                              void* d_out, int out_size, void* d_ws, size_t ws_size,
                              hipStream_t stream) {
  const float* x      = (const float*)d_in[0];
  const float* conv_w = (const float*)d_in[1];
  const float* conv_b = (const float*)d_in[2];
  const float* cls    = (const float*)d_in[3];
  const float* pos    = (const float*)d_in[4];
  const float* ln1_g  = (const float*)d_in[5];
  const float* ln1_b  = (const float*)d_in[6];
  const float* qkv_w  = (const float*)d_in[7];
  const float* qkv_b  = (const float*)d_in[8];
  const float* proj_w = (const float*)d_in[9];
  const float* proj_b = (const float*)d_in[10];
  const float* ln2_g  = (const float*)d_in[11];
  const float* ln2_b  = (const float*)d_in[12];
  const float* fc1_w  = (const float*)d_in[13];
  const float* fc1_b  = (const float*)d_in[14];
  const float* fc2_w  = (const float*)d_in[15];
  const float* fc2_b  = (const float*)d_in[16];
  const float* norm_g = (const float*)d_in[17];
  const float* norm_b = (const float*)d_in[18];
  float* out = (float*)d_out;

  char* p = (char*)d_ws;
  size_t off = 0;
  auto alloc = [&](size_t bytes) { void* r = p + off; off = (off + bytes + 255) & ~(size_t)255; return r; };

  const size_t QKV_W = (size_t)DEPTH * 3 * DMODEL * DMODEL;   // 21,233,664
  const size_t PROJ_W = (size_t)DEPTH * DMODEL * DMODEL;      // 7,077,888
  const size_t FC_W = (size_t)DEPTH * FF * DMODEL;            // 28,311,552
  const size_t CONV_W = (size_t)DMODEL * DMODEL;              // 589,824

  __hip_bfloat16* wqkv = (__hip_bfloat16*)alloc(QKV_W * 2);
  __hip_bfloat16* wproj = (__hip_bfloat16*)alloc(PROJ_W * 2);
  __hip_bfloat16* wfc1 = (__hip_bfloat16*)alloc(FC_W * 2);
  __hip_bfloat16* wfc2 = (__hip_bfloat16*)alloc(FC_W * 2);
  __hip_bfloat16* wconv = (__hip_bfloat16*)alloc(CONV_W * 2);
  float* h   = (float*)alloc((size_t)MROWS * DMODEL * 4);
  __hip_bfloat16* yb = (__hip_bfloat16*)alloc((size_t)MROWS * DMODEL * 2);
  __hip_bfloat16* qkvb = (__hip_bfloat16*)alloc((size_t)MROWS * 3 * DMODEL * 2);
  __hip_bfloat16* ob = (__hip_bfloat16*)alloc((size_t)MROWS * DMODEL * 2);
  __hip_bfloat16* gb = (__hip_bfloat16*)alloc((size_t)MROWS * FF * 2);
  __hip_bfloat16* ap = (__hip_bfloat16*)alloc((size_t)MPATCH * DMODEL * 2);
  float* emb = (float*)alloc((size_t)MPATCH * DMODEL * 4);
  (void)ws_size; (void)n_in; (void)in_sizes; (void)out_size;

  auto cvt = [&](const float* src, __hip_bfloat16* dst, size_t n) {
    int n4 = (int)(n / 4);
    cvt_bf16<<<(n4 + 255) / 256, 256, 0, stream>>>((const float4*)src, (ushort4*)dst, n4);
  };
  cvt(qkv_w, wqkv, QKV_W);
  cvt(proj_w, wproj, PROJ_W);
  cvt(fc1_w, wfc1, FC_W);
  cvt(fc2_w, wfc2, FC_W);
  cvt(conv_w, wconv, CONV_W);

  // patch embed
  patch_gather<<<((long long)MPATCH * DMODEL + 255) / 256, 256, 0, stream>>>(x, ap);
  gemm_bt<float, false, false><<<dim3(DMODEL / BN, MPATCH / BM), 256, 0, stream>>>(
      ap, wconv, conv_b, emb, nullptr, MPATCH, DMODEL, DMODEL);
  assemble_h<<<((long long)MROWS * DMODEL + 255) / 256, 256, 0, stream>>>(emb, cls, pos, h);

  for (int lyr = 0; lyr < DEPTH; ++lyr) {
    ln_bf16<<<MROWS, 256, 0, stream>>>(h, ln1_g + lyr * DMODEL, ln1_b + lyr * DMODEL, yb);
    gemm_bt<__hip_bfloat16, false, false><<<dim3(3 * DMODEL / BN, MROWS / BM), 256, 0, stream>>>(
        yb, wqkv + (size_t)lyr * 3 * DMODEL * DMODEL, qkv_b + lyr * 3 * DMODEL, qkvb, nullptr,
        MROWS, 3 * DMODEL, DMODEL);
    attn_kernel<<<dim3(2, HEADS, BATCH), 256, 0, stream>>>(qkvb, ob);
    gemm_bt<float, false, true><<<dim3(DMODEL / BN, MROWS / BM), 256, 0, stream>>>(
        ob, wproj + (size_t)lyr * DMODEL * DMODEL, proj_b + lyr * DMODEL, h, h,
        MROWS, DMODEL, DMODEL);
    ln_bf16<<<MROWS, 256, 0, stream>>>(h, ln2_g + lyr * DMODEL, ln2_b + lyr * DMODEL, yb);
    gemm_bt<__hip_bfloat16, true, false><<<dim3(FF / BN, MROWS / BM), 256, 0, stream>>>(
        yb, wfc1 + (size_t)lyr * FF * DMODEL, fc1_b + lyr * FF, gb, nullptr,
        MROWS, FF, DMODEL);
    gemm_bt<float, false, true><<<dim3(DMODEL / BN, MROWS / BM), 256, 0, stream>>>(
        gb, wfc2 + (size_t)lyr * DMODEL * FF, fc2_b + lyr * DMODEL, h, h,
        MROWS, DMODEL, FF);
  }
  ln_out<<<BATCH * NTOK, 256, 0, stream>>>(h, norm_g, norm_b, out);
}

// Round 2
// 3807.143 us; speedup vs baseline: 1.8942x; 1.8942x over previous
//
#include <hip/hip_runtime.h>
#include <hip/hip_bf16.h>
#include <math.h>

// ---------------- constants ----------------
#define BATCH 32
#define DMODEL 768
#define HEADS 12
#define DH 64
#define DEPTH 12
#define FF 3072
#define NTOK 197
#define NPAD 208           // 13*16, M = 32*208 = 6656 = 52*128
#define MROWS (BATCH * NPAD)   // 6656
#define GRID14 14
#define NPATCH 196
#define MPATCH (BATCH * NPATCH) // 6272 = 49*128

typedef __attribute__((ext_vector_type(8))) short bf16x8;
typedef __attribute__((ext_vector_type(4))) float f32x4;

// ---------------- fp32 -> bf16 convert ----------------
__global__ __launch_bounds__(256) void cvt_bf16(const float4* __restrict__ in,
                                                ushort4* __restrict__ out, int n4) {
  int i = blockIdx.x * 256 + threadIdx.x;
  if (i < n4) {
    float4 v = in[i];
    __hip_bfloat16 a = __float2bfloat16(v.x), b = __float2bfloat16(v.y);
    __hip_bfloat16 c = __float2bfloat16(v.z), d = __float2bfloat16(v.w);
    ushort4 r;
    r.x = *(unsigned short*)&a; r.y = *(unsigned short*)&b;
    r.z = *(unsigned short*)&c; r.w = *(unsigned short*)&d;
    out[i] = r;
  }
}

// ---------------- patch gather: x[b,c,224,224] -> A[6272][768] bf16 ----------------
__global__ __launch_bounds__(256) void patch_gather(const float* __restrict__ x,
                                                    __hip_bfloat16* __restrict__ ap) {
  long long idx = (long long)blockIdx.x * 256 + threadIdx.x;
  if (idx >= (long long)MPATCH * DMODEL) return;
  int k = (int)(idx % DMODEL);
  int m = (int)(idx / DMODEL);
  int b = m / NPATCH, g = m % NPATCH;
  int gh = g / GRID14, gw = g % GRID14;
  int c = k >> 8, r = k & 255, p = r >> 4, q = r & 15;
  float v = x[(((long long)(b * 3 + c) * 224) + gh * 16 + p) * 224 + gw * 16 + q];
  ap[idx] = __float2bfloat16(v);
}

// ---------------- assemble h: cls/emb + pos, pads = 0 ----------------
__global__ __launch_bounds__(256) void assemble_h(const float* __restrict__ emb,
                                                  const float* __restrict__ cls,
                                                  const float* __restrict__ pos,
                                                  float* __restrict__ h) {
  long long idx = (long long)blockIdx.x * 256 + threadIdx.x;
  if (idx >= (long long)MROWS * DMODEL) return;
  int d = (int)(idx % DMODEL);
  int row = (int)(idx / DMODEL);
  int n = row % NPAD, b = row / NPAD;
  float v;
  if (n == 0) v = cls[d] + pos[d];
  else if (n <= NPATCH) v = emb[((long long)b * NPATCH + (n - 1)) * DMODEL + d] + pos[(long long)n * DMODEL + d];
  else v = 0.f;
  h[idx] = v;
}

// ---------------- LayerNorm (fp32 in -> bf16 out), one block per row ----------------
__global__ __launch_bounds__(256) void ln_bf16(const float* __restrict__ x,
                                               const float* __restrict__ g,
                                               const float* __restrict__ bt,
                                               __hip_bfloat16* __restrict__ y) {
  int row = blockIdx.x, t = threadIdx.x;
  const float* xr = x + (long long)row * DMODEL;
  float x0 = xr[t], x1 = xr[t + 256], x2 = xr[t + 512];
  float s = x0 + x1 + x2, ss = x0 * x0 + x1 * x1 + x2 * x2;
  for (int off = 32; off; off >>= 1) { s += __shfl_xor(s, off); ss += __shfl_xor(ss, off); }
  __shared__ float red[8];
  int w = t >> 6;
  if ((t & 63) == 0) { red[w] = s; red[w + 4] = ss; }
  __syncthreads();
  s = red[0] + red[1] + red[2] + red[3];
  ss = red[4] + red[5] + red[6] + red[7];
  float mu = s * (1.f / DMODEL);
  float inv = rsqrtf(ss * (1.f / DMODEL) - mu * mu + 1e-6f);
  long long base = (long long)row * DMODEL;
  y[base + t]       = __float2bfloat16((x0 - mu) * inv * g[t] + bt[t]);
  y[base + t + 256] = __float2bfloat16((x1 - mu) * inv * g[t + 256] + bt[t + 256]);
  y[base + t + 512] = __float2bfloat16((x2 - mu) * inv * g[t + 512] + bt[t + 512]);
}

// ---------------- final LayerNorm -> fp32 packed [B,197,768] ----------------
__global__ __launch_bounds__(256) void ln_out(const float* __restrict__ x,
                                              const float* __restrict__ g,
                                              const float* __restrict__ bt,
                                              float* __restrict__ out) {
  int idx = blockIdx.x, t = threadIdx.x;
  int b = idx / NTOK, n = idx % NTOK;
  const float* xr = x + ((long long)b * NPAD + n) * DMODEL;
  float x0 = xr[t], x1 = xr[t + 256], x2 = xr[t + 512];
  float s = x0 + x1 + x2, ss = x0 * x0 + x1 * x1 + x2 * x2;
  for (int off = 32; off; off >>= 1) { s += __shfl_xor(s, off); ss += __shfl_xor(ss, off); }
  __shared__ float red[8];
  int w = t >> 6;
  if ((t & 63) == 0) { red[w] = s; red[w + 4] = ss; }
  __syncthreads();
  s = red[0] + red[1] + red[2] + red[3];
  ss = red[4] + red[5] + red[6] + red[7];
  float mu = s * (1.f / DMODEL);
  float inv = rsqrtf(ss * (1.f / DMODEL) - mu * mu + 1e-6f);
  long long base = (long long)idx * DMODEL;
  out[base + t]       = (x0 - mu) * inv * g[t] + bt[t];
  out[base + t + 256] = (x1 - mu) * inv * g[t + 256] + bt[t + 256];
  out[base + t + 512] = (x2 - mu) * inv * g[t + 512] + bt[t + 512];
}

// ---------------- MFMA GEMM: C[m,n] = sum_k A[m,k]*B[n,k] + bias[n] ----------------
#define BM 128
#define BN 128
#define BKK 64

__device__ __forceinline__ void stage_tile(const __hip_bfloat16* __restrict__ g, int ldg,
                                           __hip_bfloat16* lds, int w, int l) {
#pragma unroll
  for (int c = 0; c < 4; ++c) {
    int rb = (c * 4 + w) * 8;                     // wave-uniform row base
    const __hip_bfloat16* gp = g + (long long)(rb + (l >> 3)) * ldg + (l & 7) * 8;
    __builtin_amdgcn_global_load_lds(
        (const __attribute__((address_space(1))) unsigned int*)(const void*)gp,
        (__attribute__((address_space(3))) unsigned int*)(void*)(lds + rb * BKK), 16, 0, 0);
  }
}

__device__ __forceinline__ void store_out(float* p, float v) { *p = v; }
__device__ __forceinline__ void store_out(__hip_bfloat16* p, float v) { *p = __float2bfloat16(v); }

template <typename OutT, bool GELU_ACT, bool RESID>
__global__ __launch_bounds__(256) void gemm_bt(const __hip_bfloat16* __restrict__ A,
                                               const __hip_bfloat16* __restrict__ Bw,
                                               const float* __restrict__ bias,
                                               OutT* __restrict__ C,
                                               const float* __restrict__ res,
                                               int M, int N, int K) {
  __shared__ __hip_bfloat16 As[BM * BKK];
  __shared__ __hip_bfloat16 Bs[BN * BKK];
  int tid = threadIdx.x, l = tid & 63, w = tid >> 6;
  int wr = w >> 1, wc = w & 1;
  int bm0 = blockIdx.y * BM, bn0 = blockIdx.x * BN;
  f32x4 acc[4][4] = {};
  for (int kt = 0; kt < K; kt += BKK) {
    __syncthreads();
    stage_tile(A + (long long)bm0 * K + kt, K, As, w, l);
    stage_tile(Bw + (long long)bn0 * K + kt, K, Bs, w, l);
    __syncthreads();
    int lr = l & 15;
#pragma unroll
    for (int ks = 0; ks < 2; ++ks) {
      int lk = ks * 32 + (l >> 4) * 8;
      bf16x8 a[4], b[4];
#pragma unroll
      for (int i = 0; i < 4; ++i)
        a[i] = *(const bf16x8*)&As[(wr * 64 + i * 16 + lr) * BKK + lk];
#pragma unroll
      for (int i = 0; i < 4; ++i)
        b[i] = *(const bf16x8*)&Bs[(wc * 64 + i * 16 + lr) * BKK + lk];
#pragma unroll
      for (int i = 0; i < 4; ++i)
#pragma unroll
        for (int j = 0; j < 4; ++j)
          acc[i][j] = __builtin_amdgcn_mfma_f32_16x16x32_bf16(a[i], b[j], acc[i][j], 0, 0, 0);
    }
  }
  int lr = l & 15, lq = l >> 4;
#pragma unroll
  for (int i = 0; i < 4; ++i) {
#pragma unroll
    for (int j = 0; j < 4; ++j) {
      int col = bn0 + wc * 64 + j * 16 + lr;
      float bv = bias[col];
#pragma unroll
      for (int r = 0; r < 4; ++r) {
        int row = bm0 + wr * 64 + i * 16 + lq * 4 + r;
        float v = acc[i][j][r] + bv;
        if (GELU_ACT) v = 0.5f * v * (1.f + erff(v * 0.70710678f));
        if (RESID) v += res[(long long)row * N + col];
        store_out(&C[(long long)row * N + col], v);
      }
    }
  }
}

// ---------------- MFMA flash attention: block per (head, batch) ----------------
// LDS layout (ushort units):
//   K  [208][72]   rows m, stride 72  (144B: 16B-aligned, 2-way banks)
//   V^T[64][232]   rows d, stride 232 (464B: 16B-aligned, ~2-way banks), zeros m>=197
//   P  [4][16][232] per-wave, cols 208..223 zeroed once (tail MFMA reads them)
#define ALD_K 0
#define ALD_V 14976                 // 208*72
#define ALD_P 29824                 // + 64*232
#define ALD_TOT 44672               // + 4*16*232  (= 89,344 bytes)

__global__ __launch_bounds__(256) void attn_mfma(const __hip_bfloat16* __restrict__ qkv,
                                                 __hip_bfloat16* __restrict__ o) {
  __shared__ unsigned short sm[ALD_TOT];
  const int h = blockIdx.x, b = blockIdx.y;
  const int tid = threadIdx.x, l = tid & 63, w = tid >> 6;
  const int lr = l & 15, hi = l >> 4;
  const unsigned short* q16 = (const unsigned short*)qkv;
  unsigned short* o16 = (unsigned short*)o;
  const long long bb = (long long)b * NPAD * 2304 + h * 64;

  // ---- stage K rows 0..207 (pad rows finite; masked later) ----
  for (int r = tid >> 3; r < NPAD; r += 32) {
    int d = (tid & 7) * 8;
    *(bf16x8*)&sm[ALD_K + r * 72 + d] =
        *(const bf16x8*)&q16[bb + (long long)r * 2304 + 768 + d];
  }
  // ---- stage V^T rows d, cols m 0..196 ----
  for (int m = tid >> 3; m < NTOK; m += 32) {
    int d0 = (tid & 7) * 8;
    bf16x8 v = *(const bf16x8*)&q16[bb + (long long)m * 2304 + 1536 + d0];
#pragma unroll
    for (int j = 0; j < 8; ++j) sm[ALD_V + (d0 + j) * 232 + m] = ((short*)&v)[j];
  }
  // ---- zero V^T cols 197..223 (tail MFMA reads these; avoid NaN*0) ----
  for (int i = tid; i < 64 * 27; i += 256) {
    int d = i / 27, m = 197 + i % 27;
    sm[ALD_V + d * 232 + m] = 0;
  }
  // ---- zero P cols 208..223 for all 4 waves ----
  for (int i = tid; i < 4 * 16 * 16; i += 256) {
    int wv = i >> 8, rr = (i >> 4) & 15, cc = i & 15;
    sm[ALD_P + wv * (16 * 232) + rr * 232 + 208 + cc] = 0;
  }
  __syncthreads();

  unsigned short* Pw = &sm[ALD_P + w * (16 * 232)];
  for (int qt = w; qt < 13; qt += 4) {
    // Q A-fragments straight from global (L2-resident)
    bf16x8 qf0 = *(const bf16x8*)&q16[bb + (long long)(qt * 16 + lr) * 2304 + hi * 8];
    bf16x8 qf1 = *(const bf16x8*)&q16[bb + (long long)(qt * 16 + lr) * 2304 + hi * 8 + 32];
    // ---- S = Q K^T over 13 column tiles ----
    f32x4 s[13];
#pragma unroll
    for (int ct = 0; ct < 13; ++ct) {
      bf16x8 k0 = *(const bf16x8*)&sm[ALD_K + (ct * 16 + lr) * 72 + hi * 8];
      bf16x8 k1 = *(const bf16x8*)&sm[ALD_K + (ct * 16 + lr) * 72 + hi * 8 + 32];
      f32x4 z = {0.f, 0.f, 0.f, 0.f};
      z = __builtin_amdgcn_mfma_f32_16x16x32_bf16(qf0, k0, z, 0, 0, 0);
      z = __builtin_amdgcn_mfma_f32_16x16x32_bf16(qf1, k1, z, 0, 0, 0);
      s[ct] = z;
    }
    // ---- scale, mask cols >= 197, row-softmax ----
    float mx[4] = {-1e30f, -1e30f, -1e30f, -1e30f};
#pragma unroll
    for (int ct = 0; ct < 13; ++ct)
#pragma unroll
      for (int r = 0; r < 4; ++r) {
        float v = s[ct][r] * 0.125f;
        if (ct == 12 && lr > 4) v = -1e30f;
        s[ct][r] = v;
        mx[r] = fmaxf(mx[r], v);
      }
#pragma unroll
    for (int r = 0; r < 4; ++r) {
      mx[r] = fmaxf(mx[r], __shfl_xor(mx[r], 1));
      mx[r] = fmaxf(mx[r], __shfl_xor(mx[r], 2));
      mx[r] = fmaxf(mx[r], __shfl_xor(mx[r], 4));
      mx[r] = fmaxf(mx[r], __shfl_xor(mx[r], 8));
    }
    float sum[4] = {0.f, 0.f, 0.f, 0.f};
#pragma unroll
    for (int ct = 0; ct < 13; ++ct)
#pragma unroll
      for (int r = 0; r < 4; ++r) {
        float pv = __expf(s[ct][r] - mx[r]);
        s[ct][r] = pv;
        sum[r] += pv;
      }
#pragma unroll
    for (int r = 0; r < 4; ++r) {
      sum[r] += __shfl_xor(sum[r], 1);
      sum[r] += __shfl_xor(sum[r], 2);
      sum[r] += __shfl_xor(sum[r], 4);
      sum[r] += __shfl_xor(sum[r], 8);
    }
    float inv[4];
#pragma unroll
    for (int r = 0; r < 4; ++r) inv[r] = 1.f / sum[r];
    // ---- write P (bf16) to this wave's LDS buffer ----
#pragma unroll
    for (int ct = 0; ct < 13; ++ct)
#pragma unroll
      for (int r = 0; r < 4; ++r) {
        __hip_bfloat16 pb = __float2bfloat16(s[ct][r] * inv[r]);
        Pw[(hi * 4 + r) * 232 + ct * 16 + lr] = *(unsigned short*)&pb;
      }
    // ---- O = P V : 7 k-steps of 32 (m 208..223 are exact zeros) ----
    f32x4 oacc[4] = {};
#pragma unroll
    for (int kst = 0; kst < 7; ++kst) {
      bf16x8 pa = *(const bf16x8*)&Pw[lr * 232 + kst * 32 + hi * 8];
#pragma unroll
      for (int dt = 0; dt < 4; ++dt) {
        bf16x8 vb = *(const bf16x8*)&sm[ALD_V + (dt * 16 + lr) * 232 + kst * 32 + hi * 8];
        oacc[dt] = __builtin_amdgcn_mfma_f32_16x16x32_bf16(pa, vb, oacc[dt], 0, 0, 0);
      }
    }
    // ---- write O tile ----
#pragma unroll
    for (int dt = 0; dt < 4; ++dt)
#pragma unroll
      for (int r = 0; r < 4; ++r) {
        __hip_bfloat16 obv = __float2bfloat16(oacc[dt][r]);
        o16[((long long)b * NPAD + qt * 16 + hi * 4 + r) * DMODEL + h * 64 + dt * 16 + lr] =
            *(unsigned short*)&obv;
      }
  }
}

// ---------------- host launch ----------------
extern "C" void kernel_launch(void* const* d_in, const int* in_sizes, int n_in,
                              void* d_out, int out_size, void* d_ws, size_t ws_size,
                              hipStream_t stream) {
  const float* x      = (const float*)d_in[0];
  const float* conv_w = (const float*)d_in[1];
  const float* conv_b = (const float*)d_in[2];
  const float* cls    = (const float*)d_in[3];
  const float* pos    = (const float*)d_in[4];
  const float* ln1_g  = (const float*)d_in[5];
  const float* ln1_b  = (const float*)d_in[6];
  const float* qkv_w  = (const float*)d_in[7];
  const float* qkv_b  = (const float*)d_in[8];
  const float* proj_w = (const float*)d_in[9];
  const float* proj_b = (const float*)d_in[10];
  const float* ln2_g  = (const float*)d_in[11];
  const float* ln2_b  = (const float*)d_in[12];
  const float* fc1_w  = (const float*)d_in[13];
  const float* fc1_b  = (const float*)d_in[14];
  const float* fc2_w  = (const float*)d_in[15];
  const float* fc2_b  = (const float*)d_in[16];
  const float* norm_g = (const float*)d_in[17];
  const float* norm_b = (const float*)d_in[18];
  float* out = (float*)d_out;

  char* p = (char*)d_ws;
  size_t off = 0;
  auto alloc = [&](size_t bytes) { void* r = p + off; off = (off + bytes + 255) & ~(size_t)255; return r; };

  const size_t QKV_W = (size_t)DEPTH * 3 * DMODEL * DMODEL;   // 21,233,664
  const size_t PROJ_W = (size_t)DEPTH * DMODEL * DMODEL;      // 7,077,888
  const size_t FC_W = (size_t)DEPTH * FF * DMODEL;            // 28,311,552
  const size_t CONV_W = (size_t)DMODEL * DMODEL;              // 589,824

  __hip_bfloat16* wqkv = (__hip_bfloat16*)alloc(QKV_W * 2);
  __hip_bfloat16* wproj = (__hip_bfloat16*)alloc(PROJ_W * 2);
  __hip_bfloat16* wfc1 = (__hip_bfloat16*)alloc(FC_W * 2);
  __hip_bfloat16* wfc2 = (__hip_bfloat16*)alloc(FC_W * 2);
  __hip_bfloat16* wconv = (__hip_bfloat16*)alloc(CONV_W * 2);
  float* h   = (float*)alloc((size_t)MROWS * DMODEL * 4);
  __hip_bfloat16* yb = (__hip_bfloat16*)alloc((size_t)MROWS * DMODEL * 2);
  __hip_bfloat16* qkvb = (__hip_bfloat16*)alloc((size_t)MROWS * 3 * DMODEL * 2);
  __hip_bfloat16* ob = (__hip_bfloat16*)alloc((size_t)MROWS * DMODEL * 2);
  __hip_bfloat16* gb = (__hip_bfloat16*)alloc((size_t)MROWS * FF * 2);
  __hip_bfloat16* ap = (__hip_bfloat16*)alloc((size_t)MPATCH * DMODEL * 2);
  float* emb = (float*)alloc((size_t)MPATCH * DMODEL * 4);
  (void)ws_size; (void)n_in; (void)in_sizes; (void)out_size;

  auto cvt = [&](const float* src, __hip_bfloat16* dst, size_t n) {
    int n4 = (int)(n / 4);
    cvt_bf16<<<(n4 + 255) / 256, 256, 0, stream>>>((const float4*)src, (ushort4*)dst, n4);
  };
  cvt(qkv_w, wqkv, QKV_W);
  cvt(proj_w, wproj, PROJ_W);
  cvt(fc1_w, wfc1, FC_W);
  cvt(fc2_w, wfc2, FC_W);
  cvt(conv_w, wconv, CONV_W);

  // patch embed
  patch_gather<<<((long long)MPATCH * DMODEL + 255) / 256, 256, 0, stream>>>(x, ap);
  gemm_bt<float, false, false><<<dim3(DMODEL / BN, MPATCH / BM), 256, 0, stream>>>(
      ap, wconv, conv_b, emb, nullptr, MPATCH, DMODEL, DMODEL);
  assemble_h<<<((long long)MROWS * DMODEL + 255) / 256, 256, 0, stream>>>(emb, cls, pos, h);

  for (int lyr = 0; lyr < DEPTH; ++lyr) {
    ln_bf16<<<MROWS, 256, 0, stream>>>(h, ln1_g + lyr * DMODEL, ln1_b + lyr * DMODEL, yb);
    gemm_bt<__hip_bfloat16, false, false><<<dim3(3 * DMODEL / BN, MROWS / BM), 256, 0, stream>>>(
        yb, wqkv + (size_t)lyr * 3 * DMODEL * DMODEL, qkv_b + lyr * 3 * DMODEL, qkvb, nullptr,
        MROWS, 3 * DMODEL, DMODEL);
    attn_mfma<<<dim3(HEADS, BATCH), 256, 0, stream>>>(qkvb, ob);
    gemm_bt<float, false, true><<<dim3(DMODEL / BN, MROWS / BM), 256, 0, stream>>>(
        ob, wproj + (size_t)lyr * DMODEL * DMODEL, proj_b + lyr * DMODEL, h, h,
        MROWS, DMODEL, DMODEL);
    ln_bf16<<<MROWS, 256, 0, stream>>>(h, ln2_g + lyr * DMODEL, ln2_b + lyr * DMODEL, yb);
    gemm_bt<__hip_bfloat16, true, false><<<dim3(FF / BN, MROWS / BM), 256, 0, stream>>>(
        yb, wfc1 + (size_t)lyr * FF * DMODEL, fc1_b + lyr * FF, gb, nullptr,
        MROWS, FF, DMODEL);
    gemm_bt<float, false, true><<<dim3(DMODEL / BN, MROWS / BM), 256, 0, stream>>>(
        gb, wfc2 + (size_t)lyr * DMODEL * FF, fc2_b + lyr * DMODEL, h, h,
        MROWS, DMODEL, FF);
  }
  ln_out<<<BATCH * NTOK, 256, 0, stream>>>(h, norm_g, norm_b, out);
}